// Round 5
// baseline (528.837 us; speedup 1.0000x reference)
//
#include <hip/hip_runtime.h>

#define CONT_F 13
#define CATE_F 26
#define FF 39
#define DD 40
#define NCOMB 741
#define BB 2048
#define SUB0 40
#define SUB1 5
#define HH 100
#define K0 1560            // FF*DD rows of XT (e-part)
#define KTOT 5265          // K0 + NCOMB*SUB1 rows of XT
#define NPART 15
#define KCH 351            // 15*351 = 5265 exactly
#define KSUB 117           // 3*117 = 351, LDS sub-chunk
#define CPX 93             // combs per XCD

// XT layout: [KTOT][BB] floats — k-major, batch contiguous.

// ---------------------------------------------------------------- build e -> XT rows [0,1560)
__global__ __launch_bounds__(256) void build_eT_kernel(
    const float* __restrict__ conts, const int* __restrict__ cates,
    const float* __restrict__ emb, float* __restrict__ XT)
{
    const int f = blockIdx.x;
    const int b = blockIdx.y * 256 + threadIdx.x;
    float* xo = XT + (size_t)(f * DD) * BB + b;
    if (f < CONT_F) {
        const float cv = conts[b * CONT_F + f];
        const float* em = emb + f * DD;          // f uniform -> s_load row
        #pragma unroll
        for (int d = 0; d < DD; ++d)
            xo[(size_t)d * BB] = em[d] * cv;
    } else {
        const int tok = cates[b * CATE_F + (f - CONT_F)];
        const float4* er = (const float4*)(emb + (size_t)tok * DD);
        #pragma unroll
        for (int d4 = 0; d4 < DD / 4; ++d4) {
            const float4 v = er[d4];
            xo[(size_t)(d4 * 4 + 0) * BB] = v.x;
            xo[(size_t)(d4 * 4 + 1) * BB] = v.y;
            xo[(size_t)(d4 * 4 + 2) * BB] = v.z;
            xo[(size_t)(d4 * 4 + 3) * BB] = v.w;
        }
    }
}

// ---------------------------------------------------------------- subnet
// Weights staged in LDS (VGPR path, dodges the 102-SGPR s_load prefetch cap
// that left VALUBusy at 55%). ds_read_b128 broadcast: all lanes same addr.
__global__ __launch_bounds__(128, 3) void subnetT_kernel(
    const float* __restrict__ XT, const float* __restrict__ w0,
    const float* __restrict__ b0, const float* __restrict__ sln0w,
    const float* __restrict__ sln0b, const float* __restrict__ w1,
    const float* __restrict__ b1, const float* __restrict__ sln1w,
    const float* __restrict__ sln1b, float* __restrict__ XTz)
{
    __shared__ float lw[3 * DD * SUB0];     // 4800 floats = 19.2 KB
    const int wgid   = blockIdx.x;
    const int xcd    = wgid & 7;
    const int within = wgid >> 3;           // 0..743: tl slow, comb fast
    const int c_loc  = within % CPX;
    const int tl     = within / CPX;        // 0..7 (256-row tiles)
    const int c      = xcd * CPX + c_loc;
    if (c >= NCOMB) return;                 // block-uniform (before barrier: OK)
    const int col = tl * 256 + threadIdx.x * 2;

    // stage w0[c] into LDS, coalesced
    {
        const float* wsrc = w0 + c * (3 * DD * SUB0);
        for (int i = threadIdx.x; i < 3 * DD * SUB0; i += 128)
            lw[i] = wsrc[i];
    }
    __syncthreads();

    // unrank c -> (r,s)
    int r = 0, rem = c;
    while (rem >= FF - 1 - r) { rem -= FF - 1 - r; ++r; }
    const int s = r + 1 + rem;

    const float* Pr = XT + (size_t)(r * DD) * BB + col;
    const float* Qr = XT + (size_t)(s * DD) * BB + col;
    const float* bc = b0 + c * SUB0;

    float acc0[SUB0], acc1[SUB0];
    #pragma unroll
    for (int o = 0; o < SUB0; ++o) { acc0[o] = bc[o]; acc1[o] = bc[o]; }

    #pragma unroll 2
    for (int d = 0; d < DD; ++d) {
        const float2 pv = *(const float2*)(Pr + (size_t)d * BB);
        const float2 qv = *(const float2*)(Qr + (size_t)d * BB);
        const float pq0 = pv.x * qv.x, pq1 = pv.y * qv.y;
        const float4* wp4 = (const float4*)(lw + d * SUB0);
        const float4* wq4 = (const float4*)(lw + 1600 + d * SUB0);
        const float4* wx4 = (const float4*)(lw + 3200 + d * SUB0);
        #pragma unroll
        for (int o4 = 0; o4 < SUB0 / 4; ++o4) {
            const float4 wp = wp4[o4];        // ds_read_b128 broadcast
            const float4 wq = wq4[o4];
            const float4 wx = wx4[o4];
            #define FMA1(comp, oo) { \
                const int o = o4 * 4 + oo; \
                float a0 = acc0[o], a1 = acc1[o]; \
                a0 = fmaf(wp.comp, pv.x, a0);  a1 = fmaf(wp.comp, pv.y, a1); \
                a0 = fmaf(wq.comp, qv.x, a0);  a1 = fmaf(wq.comp, qv.y, a1); \
                a0 = fmaf(wx.comp, pq0, a0);   a1 = fmaf(wx.comp, pq1, a1); \
                acc0[o] = a0; acc1[o] = a1; }
            FMA1(x, 0) FMA1(y, 1) FMA1(z, 2) FMA1(w, 3)
            #undef FMA1
        }
    }

    // LayerNorm(40) + relu per row, in-place
    #define LN40(acc) { \
        float m = 0.f; \
        _Pragma("unroll") for (int o = 0; o < SUB0; ++o) m += acc[o]; \
        m *= (1.f / SUB0); \
        float v = 0.f; \
        _Pragma("unroll") for (int o = 0; o < SUB0; ++o) { const float dl = acc[o] - m; v += dl * dl; } \
        v *= (1.f / SUB0); \
        const float inv = rsqrtf(v + 1e-5f); \
        _Pragma("unroll") for (int o = 0; o < SUB0; ++o) { \
            const float t = (acc[o] - m) * inv * sln0w[o] + sln0b[o]; \
            acc[o] = t > 0.f ? t : 0.f; } }
    LN40(acc0)
    LN40(acc1)
    #undef LN40

    // 40 -> 5
    const float* w1c = w1 + c * (SUB0 * SUB1);
    float a20[SUB1], a21[SUB1];
    #pragma unroll
    for (int j = 0; j < SUB1; ++j) { a20[j] = b1[c * SUB1 + j]; a21[j] = a20[j]; }
    #pragma unroll
    for (int k = 0; k < SUB0; ++k) {
        #pragma unroll
        for (int j = 0; j < SUB1; ++j) {
            const float wv = w1c[k * SUB1 + j];
            a20[j] = fmaf(wv, acc0[k], a20[j]);
            a21[j] = fmaf(wv, acc1[k], a21[j]);
        }
    }

    // LayerNorm(5) + relu -> XT rows K0 + c*5 + j, coalesced float2 stores
    #define LN5(a2) { \
        float m2 = 0.f; \
        _Pragma("unroll") for (int j = 0; j < SUB1; ++j) m2 += a2[j]; \
        m2 *= (1.f / SUB1); \
        float v2 = 0.f; \
        _Pragma("unroll") for (int j = 0; j < SUB1; ++j) { const float dl = a2[j] - m2; v2 += dl * dl; } \
        v2 *= (1.f / SUB1); \
        const float inv2 = rsqrtf(v2 + 1e-5f); \
        _Pragma("unroll") for (int j = 0; j < SUB1; ++j) \
            a2[j] = fmaxf((a2[j] - m2) * inv2 * sln1w[j] + sln1b[j], 0.f); }
    LN5(a20)
    LN5(a21)
    #undef LN5

    float* zo = XTz + (size_t)(K0 + c * SUB1) * BB + col;
    #pragma unroll
    for (int j = 0; j < SUB1; ++j) {
        float2 st; st.x = a20[j]; st.y = a21[j];
        *(float2*)(zo + (size_t)j * BB) = st;
    }
}

// ---------------------------------------------------------------- fc0 partials
// thread = (h-half hg, batch lane of 128). Weight sub-chunk (117 k-rows x 100,
// padded to 104 so each 50-wide half starts 16B-aligned) staged in LDS,
// broadcast float4 reads; XT reads coalesced across lanes.
__global__ __launch_bounds__(256) void fc0_partialT_kernel(
    const float* __restrict__ XT, const float* __restrict__ w,
    float* __restrict__ partial)
{
    __shared__ float ws[KSUB * 104];         // 48.7 KB
    const int bt = blockIdx.x;               // 0..15 (128 rows each)
    const int kc = blockIdx.y;               // 0..14
    const int l  = threadIdx.x & 127;
    const int hg = threadIdx.x >> 7;         // 0/1 -> h in [0,50)/[50,100)
    const int b  = bt * 128 + l;

    float acc[50];
    #pragma unroll
    for (int j = 0; j < 50; ++j) acc[j] = 0.f;

    for (int ph = 0; ph < 3; ++ph) {
        const int k0 = kc * KCH + ph * KSUB;
        __syncthreads();                     // protect previous phase's reads
        for (int i = threadIdx.x; i < KSUB * 100; i += 256) {
            const int rr = i / 100, h = i % 100;
            ws[rr * 104 + (h < 50 ? h : h + 2)] = w[(size_t)(k0 + rr) * HH + h];
        }
        __syncthreads();

        const float* xp = XT + (size_t)k0 * BB + b;
        const float* wrow = ws + hg * 52;    // byte offset 0 / 208, both 16B-aligned
        for (int rr = 0; rr < KSUB; ++rr) {
            const float xv = xp[(size_t)rr * BB];          // coalesced
            const float4* w4 = (const float4*)(wrow + rr * 104);
            #pragma unroll
            for (int j4 = 0; j4 < 12; ++j4) {
                const float4 wv = w4[j4];                  // broadcast b128
                acc[j4 * 4 + 0] = fmaf(wv.x, xv, acc[j4 * 4 + 0]);
                acc[j4 * 4 + 1] = fmaf(wv.y, xv, acc[j4 * 4 + 1]);
                acc[j4 * 4 + 2] = fmaf(wv.z, xv, acc[j4 * 4 + 2]);
                acc[j4 * 4 + 3] = fmaf(wv.w, xv, acc[j4 * 4 + 3]);
            }
            const float2 w2 = *(const float2*)(wrow + rr * 104 + 48);
            acc[48] = fmaf(w2.x, xv, acc[48]);
            acc[49] = fmaf(w2.y, xv, acc[49]);
        }
    }

    // partial[kc][b][hg*50 + j]; float2 stores (hg=1 base is 8B-aligned only)
    float* po = partial + ((size_t)kc * BB + b) * HH + hg * 50;
    #pragma unroll
    for (int j2 = 0; j2 < 25; ++j2) {
        float2 st; st.x = acc[j2 * 2]; st.y = acc[j2 * 2 + 1];
        *(float2*)(po + j2 * 2) = st;
    }
}

// ---------------------------------------------------------------- fused fc0-reduce + LN + relu + fc1 + LN + out + sigmoid
__global__ __launch_bounds__(256) void fc0rh_kernel(
    const float* __restrict__ partial, const float* __restrict__ fc0b,
    const float* __restrict__ ln0w, const float* __restrict__ ln0b,
    const float* __restrict__ fc1w, const float* __restrict__ fc1b,
    const float* __restrict__ ln1w, const float* __restrict__ ln1b,
    const float* __restrict__ outw, const float* __restrict__ outb,
    float* __restrict__ out)
{
    __shared__ float xs[4][104];
    const int wl   = threadIdx.x >> 6;
    const int lane = threadIdx.x & 63;
    const int row  = blockIdx.x * 4 + wl;

    float s0 = fc0b[lane];
    float s1 = (lane < 36) ? fc0b[64 + lane] : 0.f;
    #pragma unroll
    for (int p = 0; p < NPART; ++p) {
        const float* pr = partial + ((size_t)p * BB + row) * HH;
        s0 += pr[lane];
        if (lane < 36) s1 += pr[64 + lane];
    }
    float sum = s0 + ((lane < 36) ? s1 : 0.f);
    #pragma unroll
    for (int off = 32; off; off >>= 1) sum += __shfl_xor(sum, off, 64);
    float m  = sum * 0.01f;
    float d0 = s0 - m;
    float d1 = (lane < 36) ? (s1 - m) : 0.f;
    float vs = d0 * d0 + d1 * d1;
    #pragma unroll
    for (int off = 32; off; off >>= 1) vs += __shfl_xor(vs, off, 64);
    float inv = rsqrtf(vs * 0.01f + 1e-5f);
    {
        float x0 = d0 * inv * ln0w[lane] + ln0b[lane];
        xs[wl][lane] = x0 > 0.f ? x0 : 0.f;
        if (lane < 36) {
            float x1 = d1 * inv * ln0w[64 + lane] + ln0b[64 + lane];
            xs[wl][64 + lane] = x1 > 0.f ? x1 : 0.f;
        }
    }

    float a0 = fc1b[lane];
    float a1 = (lane < 36) ? fc1b[64 + lane] : 0.f;
    for (int k = 0; k < HH; ++k) {
        const float xv = xs[wl][k];
        a0 = fmaf(fc1w[k * HH + lane], xv, a0);
        if (lane < 36) a1 = fmaf(fc1w[k * HH + 64 + lane], xv, a1);
    }
    sum = a0 + ((lane < 36) ? a1 : 0.f);
    #pragma unroll
    for (int off = 32; off; off >>= 1) sum += __shfl_xor(sum, off, 64);
    m  = sum * 0.01f;
    d0 = a0 - m;
    d1 = (lane < 36) ? (a1 - m) : 0.f;
    vs = d0 * d0 + d1 * d1;
    #pragma unroll
    for (int off = 32; off; off >>= 1) vs += __shfl_xor(vs, off, 64);
    inv = rsqrtf(vs * 0.01f + 1e-5f);

    float x0 = d0 * inv * ln1w[lane] + ln1b[lane];
    x0 = x0 > 0.f ? x0 : 0.f;
    float t = x0 * outw[lane];
    if (lane < 36) {
        float x1 = d1 * inv * ln1w[64 + lane] + ln1b[64 + lane];
        x1 = x1 > 0.f ? x1 : 0.f;
        t = fmaf(x1, outw[64 + lane], t);
    }
    #pragma unroll
    for (int off = 32; off; off >>= 1) t += __shfl_xor(t, off, 64);
    if (lane == 0) {
        const float z = t + outb[0];
        out[row] = 1.f / (1.f + expf(-z));
    }
}

// ---------------------------------------------------------------- launch
extern "C" void kernel_launch(void* const* d_in, const int* in_sizes, int n_in,
                              void* d_out, int out_size, void* d_ws, size_t ws_size,
                              hipStream_t stream)
{
    const float* conts = (const float*)d_in[0];
    const int*   cates = (const int*)d_in[1];
    const float* emb   = (const float*)d_in[3];
    const float* w0    = (const float*)d_in[4];
    const float* b0    = (const float*)d_in[5];
    const float* sln0w = (const float*)d_in[6];
    const float* sln0b = (const float*)d_in[7];
    const float* w1    = (const float*)d_in[8];
    const float* b1    = (const float*)d_in[9];
    const float* sln1w = (const float*)d_in[10];
    const float* sln1b = (const float*)d_in[11];
    const float* fc0w  = (const float*)d_in[12];
    const float* fc0b  = (const float*)d_in[13];
    const float* ln0w  = (const float*)d_in[14];
    const float* ln0b  = (const float*)d_in[15];
    const float* fc1w  = (const float*)d_in[16];
    const float* fc1b  = (const float*)d_in[17];
    const float* ln1w  = (const float*)d_in[18];
    const float* ln1b  = (const float*)d_in[19];
    const float* outw  = (const float*)d_in[20];
    const float* outb  = (const float*)d_in[21];
    float* out = (float*)d_out;

    // ws: XT (5265x2048 f32 = 43.1MB) | partial (15x2048x100 = 12.3MB) => 55.4MB
    float* XT      = (float*)d_ws;
    float* partial = XT + (size_t)KTOT * BB;

    build_eT_kernel<<<dim3(FF, BB / 256), 256, 0, stream>>>(conts, cates, emb, XT);
    subnetT_kernel<<<8 * CPX * 8, 128, 0, stream>>>(
        XT, w0, b0, sln0w, sln0b, w1, b1, sln1w, sln1b, XT);
    fc0_partialT_kernel<<<dim3(BB / 128, NPART), 256, 0, stream>>>(XT, fc0w, partial);
    fc0rh_kernel<<<BB / 4, 256, 0, stream>>>(
        partial, fc0b, ln0w, ln0b, fc1w, fc1b, ln1w, ln1b, outw, outb, out);
}